// Round 5
// baseline (478.804 us; speedup 1.0000x reference)
//
#include <hip/hip_runtime.h>
#include <cstdint>
#include <cstddef>

#define TPB 256
#define BCAP 2560      // bucket capacity: mean 2046, sigma ~45 -> 11 sigma headroom
#define NBKMAX 800     // max buckets in LDS (n=100k -> 782)
#define EPB 8192       // edges per multisplit block

typedef short bf16x8 __attribute__((ext_vector_type(8)));
typedef float f32x4 __attribute__((ext_vector_type(4)));

__device__ __forceinline__ unsigned short f2bf(float f) {
  unsigned int u = __float_as_uint(f);
  unsigned int r = (u + 0x7fffu + ((u >> 16) & 1u)) >> 16;  // RNE
  return (unsigned short)r;
}
__device__ __forceinline__ float bf2f(unsigned short h) {
  return __uint_as_float(((unsigned int)h) << 16);
}

// async 16B global->LDS DMA. LDS dest is wave-uniform base + lane*16.
__device__ __forceinline__ void gload16(const void* g, void* l) {
  __builtin_amdgcn_global_load_lds(
      (const __attribute__((address_space(1))) unsigned int*)g,
      (__attribute__((address_space(3))) unsigned int*)l, 16, 0, 0);
}

// counted vmcnt wait: wait until <= N vector-memory ops outstanding.
template <int N>
__device__ __forceinline__ void waitvm() {
  asm volatile("s_waitcnt vmcnt(%0)" ::"n"(N) : "memory");
}

// ---------------- bucketed CSR build (multisplit, R4-proven) ----------------

__global__ __launch_bounds__(256) void multisplit_scatter(
    const int* __restrict__ src, const int* __restrict__ dst,
    unsigned int* __restrict__ be, int* __restrict__ bcnt, int e, int nbk) {
  __shared__ int hist[NBKMAX];
  __shared__ int curs[NBKMAX];
  int tx = threadIdx.x;
  int e0 = blockIdx.x * EPB;
  int e1 = min(e, e0 + EPB);

  for (int b = tx; b < nbk; b += TPB) hist[b] = 0;
  __syncthreads();
  for (int i = e0 + tx; i < e1; i += TPB) atomicAdd(&hist[dst[i] >> 7], 1);
  __syncthreads();
  int rot = (blockIdx.x * 131) % nbk;
  for (int s = tx; s < nbk; s += TPB) {
    int b = s + rot;
    if (b >= nbk) b -= nbk;
    int h = hist[b];
    curs[b] = (h > 0) ? atomicAdd(&bcnt[b], h) : 0;
  }
  __syncthreads();
  for (int i = e0 + tx; i < e1; i += TPB) {
    int d = dst[i];
    int b = d >> 7;
    int p = atomicAdd(&curs[b], 1);
    if (p < BCAP)
      be[(size_t)b * BCAP + p] = ((unsigned int)(d & 127) << 17) | (unsigned int)src[i];
  }
}

__global__ void bucket_scan(const int* __restrict__ bcnt, int* __restrict__ bbase, int nbk) {
  __shared__ int s[TPB];
  __shared__ int carry;
  int tx = threadIdx.x;
  if (tx == 0) carry = 0;
  __syncthreads();
  for (int base = 0; base < nbk; base += TPB) {
    int i = base + tx;
    int v = (i < nbk) ? bcnt[i] : 0;
    s[tx] = v;
    __syncthreads();
    for (int d = 1; d < TPB; d <<= 1) {
      int t = (tx >= d) ? s[tx - d] : 0;
      __syncthreads();
      s[tx] += t;
      __syncthreads();
    }
    int c = carry;
    if (i < nbk) bbase[i] = c + s[tx] - v;
    __syncthreads();
    if (tx == TPB - 1) carry = c + s[tx];
    __syncthreads();
  }
}

__global__ __launch_bounds__(256) void per_bucket_build(
    const unsigned int* __restrict__ be, const int* __restrict__ bcnt,
    const int* __restrict__ bbase, int* __restrict__ off, int* __restrict__ col,
    int n, int e) {
  int b = blockIdx.x, tx = threadIdx.x;
  int cnt = bcnt[b];
  if (cnt > BCAP) cnt = BCAP;
  int base = bbase[b];
  int node0 = b << 7;
  __shared__ int scnt[128];
  __shared__ int sscan[128];
  if (tx < 128) scnt[tx] = 0;
  __syncthreads();
  const unsigned int* eb = be + (size_t)b * BCAP;
  for (int i = tx; i < cnt; i += 256) atomicAdd(&scnt[eb[i] >> 17], 1);
  __syncthreads();
  if (tx < 128) sscan[tx] = scnt[tx];
  __syncthreads();
  for (int d = 1; d < 128; d <<= 1) {
    int t = 0;
    if (tx < 128 && tx >= d) t = sscan[tx - d];
    __syncthreads();
    if (tx < 128) sscan[tx] += t;
    __syncthreads();
  }
  if (tx < 128) {
    int excl = sscan[tx] - scnt[tx];
    if (node0 + tx < n) off[node0 + tx] = base + excl;
    scnt[tx] = excl;  // becomes fill cursor
  }
  if (b == 0 && tx == 0) off[n] = e;
  __syncthreads();
  for (int i = tx; i < cnt; i += 256) {
    unsigned int u = eb[i];
    int p = atomicAdd(&scnt[u >> 17], 1);
    col[base + p] = (int)(u & 0x1ffff);
  }
}

// ---------------- converts ----------------

__global__ void f32_to_bf16_v4(const float* __restrict__ in, unsigned short* __restrict__ out,
                               int n4) {
  int i = blockIdx.x * TPB + threadIdx.x;
  if (i >= n4) return;
  float4 v = ((const float4*)in)[i];
  ushort4 o;
  o.x = f2bf(v.x); o.y = f2bf(v.y); o.z = f2bf(v.z); o.w = f2bf(v.w);
  ((ushort4*)out)[i] = o;
}

__global__ void make_dropmask(const float* __restrict__ u, unsigned char* __restrict__ m,
                              int n4) {
  int i = blockIdx.x * TPB + threadIdx.x;
  if (i >= n4) return;
  float4 v = ((const float4*)u)[i];
  uchar4 o;
  o.x = (v.x >= 0.2f) ? 1 : 0;
  o.y = (v.y >= 0.2f) ? 1 : 0;
  o.z = (v.z >= 0.2f) ? 1 : 0;
  o.w = (v.w >= 0.2f) ? 1 : 0;
  ((uchar4*)m)[i] = o;
}

// layer-1 weights: Wt1[128 out][256 K] = concat(W1l;W1r) transposed
template <int NF>
__global__ void build_wt(const float* __restrict__ Wl, const float* __restrict__ Wr,
                         unsigned short* __restrict__ Wt) {
  int idx = blockIdx.x * TPB + threadIdx.x;
  if (idx >= NF * 256) return;
  int nn = idx >> 8;
  int k = idx & 255;
  float v = (k < 128) ? Wl[k * NF + nn] : Wr[(k - 128) * NF + nn];
  Wt[idx] = f2bf(v);
}

// layer-2' weights: Wt2[128 out][128 K]; rows 0-63 = W2l^T (-> P), 64-127 = W2r^T (-> Q)
__global__ void build_wt2p(const float* __restrict__ W2l, const float* __restrict__ W2r,
                           unsigned short* __restrict__ Wt) {
  int idx = blockIdx.x * TPB + threadIdx.x;
  if (idx >= 128 * 128) return;
  int nn = idx >> 7;
  int k = idx & 127;
  float v = (nn < 64) ? W2l[k * 64 + nn] : W2r[k * 64 + (nn - 64)];
  Wt[idx] = f2bf(v);
}

// ---------------- layer-1 mean aggregation: 2 nodes per 16-lane group ----------------
// Wave = 8 nodes (4 groups x 2 interleaved). Per chunk of 16 edges each node:
// lane li preloads colA/colB (clamped), 16 unrolled j: shfl both, gather TWO
// uint4 rows -> 32 in-flight gathers/wave (was 16; counters showed 36% VALU /
// 39% HBM = latency-bound with spare BW). Tail/short-node j's are masked via
// fmaf scale; their loads hit the clamped (cache-hot) row.

__global__ void aggregate_bf(const unsigned short* __restrict__ X,
                             const int* __restrict__ off, const int* __restrict__ col,
                             unsigned short* __restrict__ out, int n) {
  int wv = (blockIdx.x * TPB + threadIdx.x) >> 6;
  int lane = threadIdx.x & 63;
  int li = lane & 15;
  int g = lane >> 4;
  int nA = wv * 8 + g;
  int nB = wv * 8 + 4 + g;
  bool alA = nA < n, alB = nB < n;
  int s0A = 0, s1A = 0, s0B = 0, s1B = 0;
  if (alA) { s0A = off[nA]; s1A = off[nA + 1]; }
  if (alB) { s0B = off[nB]; s1B = off[nB + 1]; }
  int cntA = s1A - s0A, cntB = s1B - s0B;
  int cmax = max(cntA, cntB);

  float aA0 = 0.f, aA1 = 0.f, aA2 = 0.f, aA3 = 0.f,
        aA4 = 0.f, aA5 = 0.f, aA6 = 0.f, aA7 = 0.f;
  float aB0 = 0.f, aB1 = 0.f, aB2 = 0.f, aB3 = 0.f,
        aB4 = 0.f, aB5 = 0.f, aB6 = 0.f, aB7 = 0.f;

  for (int base = 0; base < cmax; base += 16) {
    int ciA = col[max(0, min(s0A + base + li, s1A - 1))];
    int ciB = col[max(0, min(s0B + base + li, s1B - 1))];
    int limA = cntA - base, limB = cntB - base;
#pragma unroll
    for (int j = 0; j < 16; ++j) {
      int cA = __shfl(ciA, j, 16);
      int cB = __shfl(ciB, j, 16);
      uint4 vA = *(const uint4*)(X + (size_t)cA * 128 + li * 8);
      uint4 vB = *(const uint4*)(X + (size_t)cB * 128 + li * 8);
      float sA = (j < limA) ? 1.f : 0.f;
      float sB = (j < limB) ? 1.f : 0.f;
      aA0 = fmaf(sA, __uint_as_float(vA.x << 16), aA0);
      aA1 = fmaf(sA, __uint_as_float(vA.x & 0xffff0000u), aA1);
      aA2 = fmaf(sA, __uint_as_float(vA.y << 16), aA2);
      aA3 = fmaf(sA, __uint_as_float(vA.y & 0xffff0000u), aA3);
      aA4 = fmaf(sA, __uint_as_float(vA.z << 16), aA4);
      aA5 = fmaf(sA, __uint_as_float(vA.z & 0xffff0000u), aA5);
      aA6 = fmaf(sA, __uint_as_float(vA.w << 16), aA6);
      aA7 = fmaf(sA, __uint_as_float(vA.w & 0xffff0000u), aA7);
      aB0 = fmaf(sB, __uint_as_float(vB.x << 16), aB0);
      aB1 = fmaf(sB, __uint_as_float(vB.x & 0xffff0000u), aB1);
      aB2 = fmaf(sB, __uint_as_float(vB.y << 16), aB2);
      aB3 = fmaf(sB, __uint_as_float(vB.y & 0xffff0000u), aB3);
      aB4 = fmaf(sB, __uint_as_float(vB.z << 16), aB4);
      aB5 = fmaf(sB, __uint_as_float(vB.z & 0xffff0000u), aB5);
      aB6 = fmaf(sB, __uint_as_float(vB.w << 16), aB6);
      aB7 = fmaf(sB, __uint_as_float(vB.w & 0xffff0000u), aB7);
    }
  }

  if (alA) {
    float inv = (cntA > 0) ? 1.0f / (float)cntA : 0.f;
    uint4 o;
    o.x = ((unsigned int)f2bf(aA1 * inv) << 16) | f2bf(aA0 * inv);
    o.y = ((unsigned int)f2bf(aA3 * inv) << 16) | f2bf(aA2 * inv);
    o.z = ((unsigned int)f2bf(aA5 * inv) << 16) | f2bf(aA4 * inv);
    o.w = ((unsigned int)f2bf(aA7 * inv) << 16) | f2bf(aA6 * inv);
    *(uint4*)(out + (size_t)nA * 128 + li * 8) = o;
  }
  if (alB) {
    float inv = (cntB > 0) ? 1.0f / (float)cntB : 0.f;
    uint4 o;
    o.x = ((unsigned int)f2bf(aB1 * inv) << 16) | f2bf(aB0 * inv);
    o.y = ((unsigned int)f2bf(aB3 * inv) << 16) | f2bf(aB2 * inv);
    o.z = ((unsigned int)f2bf(aB5 * inv) << 16) | f2bf(aB4 * inv);
    o.w = ((unsigned int)f2bf(aB7 * inv) << 16) | f2bf(aB6 * inv);
    *(uint4*)(out + (size_t)nB * 128 + li * 8) = o;
  }
}

// ---------------- layer-2 fused aggregate+add+ELU over P (64-dim, 128B rows) ----------
// mean commutes with W2l: out = elu(mean_j(P_j) + Q), P = h@W2l (bf16), Q = h@W2r+b2
// (f32). Rows are 128B -> 8 lanes x uint4; wave = 8 nodes; chunk of 8 edges;
// 64 in-flight gathers/wave. Gather volume halves vs aggregating h (256B rows).

__global__ void aggregate_add(const unsigned short* __restrict__ P,
                              const int* __restrict__ off, const int* __restrict__ col,
                              const float* __restrict__ Q, float* __restrict__ out, int n) {
  int wv = (blockIdx.x * TPB + threadIdx.x) >> 6;
  int lane = threadIdx.x & 63;
  int li = lane & 7;
  int node = wv * 8 + (lane >> 3);
  bool alive = node < n;
  int s0 = 0, s1 = 0;
  if (alive) { s0 = off[node]; s1 = off[node + 1]; }
  int cnt = s1 - s0;

  float a0 = 0.f, a1 = 0.f, a2 = 0.f, a3 = 0.f,
        a4 = 0.f, a5 = 0.f, a6 = 0.f, a7 = 0.f;

  for (int base = 0; base < cnt; base += 8) {
    int ci = col[max(0, min(s0 + base + li, s1 - 1))];
    int lim = cnt - base;
#pragma unroll
    for (int j = 0; j < 8; ++j) {
      int c = __shfl(ci, j, 8);
      uint4 v = *(const uint4*)(P + (size_t)c * 64 + li * 8);
      float s = (j < lim) ? 1.f : 0.f;
      a0 = fmaf(s, __uint_as_float(v.x << 16), a0);
      a1 = fmaf(s, __uint_as_float(v.x & 0xffff0000u), a1);
      a2 = fmaf(s, __uint_as_float(v.y << 16), a2);
      a3 = fmaf(s, __uint_as_float(v.y & 0xffff0000u), a3);
      a4 = fmaf(s, __uint_as_float(v.z << 16), a4);
      a5 = fmaf(s, __uint_as_float(v.z & 0xffff0000u), a5);
      a6 = fmaf(s, __uint_as_float(v.w << 16), a6);
      a7 = fmaf(s, __uint_as_float(v.w & 0xffff0000u), a7);
    }
  }

  if (alive) {
    float inv = (cnt > 0) ? 1.0f / (float)cnt : 0.f;
    const float4* qp = (const float4*)(Q + (size_t)node * 64 + li * 8);
    float4 q0 = qp[0], q1 = qp[1];
    float4 o0, o1;
    o0.x = a0 * inv + q0.x; o0.y = a1 * inv + q0.y;
    o0.z = a2 * inv + q0.z; o0.w = a3 * inv + q0.w;
    o1.x = a4 * inv + q1.x; o1.y = a5 * inv + q1.y;
    o1.z = a6 * inv + q1.z; o1.w = a7 * inv + q1.w;
    o0.x = (o0.x > 0.f) ? o0.x : expm1f(o0.x);
    o0.y = (o0.y > 0.f) ? o0.y : expm1f(o0.y);
    o0.z = (o0.z > 0.f) ? o0.z : expm1f(o0.z);
    o0.w = (o0.w > 0.f) ? o0.w : expm1f(o0.w);
    o1.x = (o1.x > 0.f) ? o1.x : expm1f(o1.x);
    o1.y = (o1.y > 0.f) ? o1.y : expm1f(o1.y);
    o1.z = (o1.z > 0.f) ? o1.z : expm1f(o1.z);
    o1.w = (o1.w > 0.f) ? o1.w : expm1f(o1.w);
    float4* op = (float4*)(out + (size_t)node * 64 + li * 8);
    op[0] = o0; op[1] = o1;
  }
}

// ---------------- MFMA GEMM: 128x64 blocks, counted-vmcnt double-buffer ----------------
// Block = 128 rows x 64 output cols (blockIdx.y picks the 64-col slab of Wt).
// NCH = K/64 chunks. MODE 0: ELU+dropout -> bf16[row][128] (layer 1).
// MODE 1: split epilogue: gcol<64 -> P bf16[row][64] (no bias), gcol>=64 ->
// Q=v+bias f32[row][64] (layer 2'). 48KB LDS -> 3 blocks/CU; pipeline: issue
// c0,c1; per chunk waitvm(6), barrier, compute, lgkmcnt(0)+barrier, issue c+2.

template <int NCH, int MODE>
__global__ __launch_bounds__(256) void gemm_mfma(
    const unsigned short* __restrict__ A1, const unsigned short* __restrict__ A2,
    const unsigned short* __restrict__ Wt, const float* __restrict__ bias,
    const unsigned char* __restrict__ dmask, unsigned short* __restrict__ outb,
    float* __restrict__ outf, int n) {
  constexpr int IPC = 6;      // DMA issues per thread per chunk: 4 A + 2 B
  constexpr int KTOT = NCH * 64;
  __shared__ __align__(16) unsigned short sA[2][128 * 64];
  __shared__ __align__(16) unsigned short sB[2][64 * 64];

  int tid = threadIdx.x;
  int row0 = blockIdx.x * 128;
  int ncol0 = blockIdx.y * 64;
  int lane = tid & 63;
  int wid = tid >> 6;
  int wm = wid >> 1, wn = wid & 1;
  int lq = lane & 15, q = lane >> 4;

  int sr = tid >> 3, sc8 = tid & 7;          // staging slot: row sr (+t*32), chunk sc8
  int cg = sc8 ^ (sr & 7);                   // global chunk this lane fetches (XOR swizzle)

  // clamped A rows for the 4 staging sub-tiles (chunk-invariant)
  int arow[4];
#pragma unroll
  for (int t = 0; t < 4; ++t) arow[t] = min(row0 + sr + t * 32, n - 1);

  f32x4 acc[4][2];
#pragma unroll
  for (int i = 0; i < 4; ++i)
#pragma unroll
    for (int j = 0; j < 2; ++j) acc[i][j] = (f32x4)(0.f);

  // issue all DMA for chunk c into buffer b (IPC insts per thread)
  auto issue = [&](int c, int b) {
    const unsigned short* Asrc = (c < 2) ? A1 : A2;
    int koff = (c & 1) * 64;
#pragma unroll
    for (int t = 0; t < 4; ++t) {
      gload16(Asrc + (size_t)arow[t] * 128 + koff + cg * 8,
              (char*)sA[b] + t * 4096 + wid * 1024);
    }
#pragma unroll
    for (int t = 0; t < 2; ++t) {
      gload16(Wt + (size_t)(ncol0 + sr + t * 32) * KTOT + c * 64 + cg * 8,
              (char*)sB[b] + t * 4096 + wid * 1024);
    }
  };

  issue(0, 0);
  issue(1, 1);

#pragma unroll
  for (int c = 0; c < NCH; ++c) {
    // wait: current chunk's IPC loads landed; next chunk's may stay in flight
    if (c < NCH - 1) waitvm<IPC>(); else waitvm<0>();
    __builtin_amdgcn_s_barrier();
    __builtin_amdgcn_sched_barrier(0);

    const int buf = c & 1;
#pragma unroll
    for (int ks = 0; ks < 2; ++ks) {
      bf16x8 a[4], b[2];
#pragma unroll
      for (int i = 0; i < 4; ++i) {
        int rr = wm * 64 + i * 16 + lq;
        a[i] = *(const bf16x8*)(&sA[buf][rr * 64 + (((ks * 4 + q) ^ (rr & 7)) * 8)]);
      }
#pragma unroll
      for (int j = 0; j < 2; ++j) {
        int rb = wn * 32 + j * 16 + lq;
        b[j] = *(const bf16x8*)(&sB[buf][rb * 64 + (((ks * 4 + q) ^ (rb & 7)) * 8)]);
      }
#pragma unroll
      for (int i = 0; i < 4; ++i)
#pragma unroll
        for (int j = 0; j < 2; ++j)
          acc[i][j] = __builtin_amdgcn_mfma_f32_16x16x32_bf16(a[i], b[j], acc[i][j], 0, 0, 0);
    }

    if (c < NCH - 2) {
      // all fragment ds_reads serviced before anyone overwrites this buffer
      asm volatile("s_waitcnt lgkmcnt(0)" ::: "memory");
      __builtin_amdgcn_sched_barrier(0);
      __builtin_amdgcn_s_barrier();
      issue(c + 2, buf);
    }
  }

#pragma unroll
  for (int j = 0; j < 2; ++j) {
    int gcol = ncol0 + wn * 32 + j * 16 + lq;
    float bv;
    if (MODE == 0) bv = bias[gcol];
    else bv = (gcol >= 64) ? bias[gcol - 64] : 0.f;
#pragma unroll
    for (int i = 0; i < 4; ++i) {
      int rbase = row0 + wm * 64 + i * 16 + q * 4;
#pragma unroll
      for (int r = 0; r < 4; ++r) {
        int row = rbase + r;
        if (row >= n) continue;
        float v = acc[i][j][r] + bv;
        if (MODE == 0) {
          v = (v > 0.f) ? v : expm1f(v);
          unsigned char k = dmask[(size_t)row * 128 + gcol];
          v = k ? v * 1.25f : 0.f;
          outb[(size_t)row * 128 + gcol] = f2bf(v);
        } else {
          if (gcol < 64) outb[(size_t)row * 64 + gcol] = f2bf(v);
          else outf[(size_t)row * 64 + (gcol - 64)] = v;
        }
      }
    }
  }
}

// ---------------- launch ----------------

extern "C" void kernel_launch(void* const* d_in, const int* in_sizes, int n_in,
                              void* d_out, int out_size, void* d_ws, size_t ws_size,
                              hipStream_t stream) {
  const float* x = (const float*)d_in[0];
  const int* ei = (const int*)d_in[1];
  const float* dropu = (const float*)d_in[2];
  const float* W1l = (const float*)d_in[3];
  const float* W1r = (const float*)d_in[4];
  const float* b1 = (const float*)d_in[5];
  const float* W2l = (const float*)d_in[6];
  const float* W2r = (const float*)d_in[7];
  const float* b2 = (const float*)d_in[8];

  int n = in_sizes[0] / 128;
  int e = in_sizes[1] / 2;
  const int* src = ei;
  const int* dst = ei + e;
  float* out = (float*)d_out;

  char* w = (char*)d_ws;
  auto alloc = [&](size_t bytes) -> char* {
    char* p = w;
    w += (bytes + 255) & ~(size_t)255;
    return p;
  };
  int nbk = (n + 127) / 128;  // buckets of 128 nodes (782)
  int* off = (int*)alloc((size_t)(n + 1) * sizeof(int));
  int* col = (int*)alloc((size_t)e * sizeof(int));
  int* bcnt = (int*)alloc((size_t)nbk * sizeof(int));
  int* bbase = (int*)alloc((size_t)nbk * sizeof(int));
  unsigned short* xb = (unsigned short*)alloc((size_t)n * 128 * 2);
  unsigned short* hb = (unsigned short*)alloc((size_t)n * 128 * 2);
  unsigned short* aggb = (unsigned short*)alloc((size_t)n * 128 * 2);
  unsigned char* dmask = (unsigned char*)alloc((size_t)n * 128);
  unsigned short* Wt1 = (unsigned short*)alloc(128 * 256 * 2);
  unsigned short* Wt2 = (unsigned short*)alloc(128 * 128 * 2);
  // overlays (stream-ordered lifetimes):
  //   be (8.0MB)  -> aggb region: dead before agg1 writes aggb
  //   pb (12.8MB) -> xb region:   xb dead after gemm1 (A2 input)
  //   qf (25.6MB) -> aggb region: aggb dead after gemm1 (A1 input)
  unsigned int* be = (unsigned int*)aggb;
  unsigned short* pb = xb;
  float* qf = (float*)aggb;

  hipMemsetAsync(bcnt, 0, (size_t)nbk * sizeof(int), stream);

  int gMS = (e + EPB - 1) / EPB;
  multisplit_scatter<<<gMS, TPB, 0, stream>>>(src, dst, be, bcnt, e, nbk);
  bucket_scan<<<1, TPB, 0, stream>>>(bcnt, bbase, nbk);
  per_bucket_build<<<nbk, TPB, 0, stream>>>(be, bcnt, bbase, off, col, n, e);

  int n4 = n * 128 / 4;
  f32_to_bf16_v4<<<(n4 + TPB - 1) / TPB, TPB, 0, stream>>>(x, xb, n4);
  make_dropmask<<<(n4 + TPB - 1) / TPB, TPB, 0, stream>>>(dropu, dmask, n4);
  build_wt<128><<<(128 * 256 + TPB - 1) / TPB, TPB, 0, stream>>>(W1l, W1r, Wt1);
  build_wt2p<<<(128 * 128 + TPB - 1) / TPB, TPB, 0, stream>>>(W2l, W2r, Wt2);

  int gAgg = (n + 31) / 32;   // 8 nodes/wave, 4 waves/block
  int gR = (n + 127) / 128;

  // layer 1: agg(x) -> gemm (K=256: [agg|x]) -> elu+drop -> hb
  aggregate_bf<<<gAgg, TPB, 0, stream>>>(xb, off, col, aggb, n);
  gemm_mfma<4, 0><<<dim3(gR, 2), TPB, 0, stream>>>(aggb, xb, Wt1, b1, dmask, hb, nullptr, n);

  // layer 2 (mean commuted with W2l): P=h@W2l (bf16), Q=h@W2r+b2 (f32),
  // out = elu(mean_j P_j + Q)
  gemm_mfma<2, 1><<<dim3(gR, 2), TPB, 0, stream>>>(hb, nullptr, Wt2, b2, nullptr, pb, qf, n);
  aggregate_add<<<gAgg, TPB, 0, stream>>>(pb, off, col, qf, out, n);
}

// Round 6
// 412.081 us; speedup vs baseline: 1.1619x; 1.1619x over previous
//
#include <hip/hip_runtime.h>
#include <cstdint>
#include <cstddef>

#define TPB 256
#define BCAP 2560      // bucket capacity: mean 2046, sigma ~45 -> 11 sigma headroom
#define NBKMAX 800     // max buckets in LDS (n=100k -> 782)
#define EPB 8192       // edges per multisplit block

typedef short bf16x8 __attribute__((ext_vector_type(8)));
typedef float f32x4 __attribute__((ext_vector_type(4)));

__device__ __forceinline__ unsigned short f2bf(float f) {
  unsigned int u = __float_as_uint(f);
  unsigned int r = (u + 0x7fffu + ((u >> 16) & 1u)) >> 16;  // RNE
  return (unsigned short)r;
}
__device__ __forceinline__ float bf2f(unsigned short h) {
  return __uint_as_float(((unsigned int)h) << 16);
}

// async 16B global->LDS DMA. LDS dest is wave-uniform base + lane*16.
__device__ __forceinline__ void gload16(const void* g, void* l) {
  __builtin_amdgcn_global_load_lds(
      (const __attribute__((address_space(1))) unsigned int*)g,
      (__attribute__((address_space(3))) unsigned int*)l, 16, 0, 0);
}

// counted vmcnt wait: wait until <= N vector-memory ops outstanding.
template <int N>
__device__ __forceinline__ void waitvm() {
  asm volatile("s_waitcnt vmcnt(%0)" ::"n"(N) : "memory");
}

// ---------------- bucketed CSR build (multisplit, R4-proven) ----------------

__global__ __launch_bounds__(256) void multisplit_scatter(
    const int* __restrict__ src, const int* __restrict__ dst,
    unsigned int* __restrict__ be, int* __restrict__ bcnt, int e, int nbk) {
  __shared__ int hist[NBKMAX];
  __shared__ int curs[NBKMAX];
  int tx = threadIdx.x;
  int e0 = blockIdx.x * EPB;
  int e1 = min(e, e0 + EPB);

  for (int b = tx; b < nbk; b += TPB) hist[b] = 0;
  __syncthreads();
  for (int i = e0 + tx; i < e1; i += TPB) atomicAdd(&hist[dst[i] >> 7], 1);
  __syncthreads();
  int rot = (blockIdx.x * 131) % nbk;
  for (int s = tx; s < nbk; s += TPB) {
    int b = s + rot;
    if (b >= nbk) b -= nbk;
    int h = hist[b];
    curs[b] = (h > 0) ? atomicAdd(&bcnt[b], h) : 0;
  }
  __syncthreads();
  for (int i = e0 + tx; i < e1; i += TPB) {
    int d = dst[i];
    int b = d >> 7;
    int p = atomicAdd(&curs[b], 1);
    if (p < BCAP)
      be[(size_t)b * BCAP + p] = ((unsigned int)(d & 127) << 17) | (unsigned int)src[i];
  }
}

__global__ void bucket_scan(const int* __restrict__ bcnt, int* __restrict__ bbase, int nbk) {
  __shared__ int s[TPB];
  __shared__ int carry;
  int tx = threadIdx.x;
  if (tx == 0) carry = 0;
  __syncthreads();
  for (int base = 0; base < nbk; base += TPB) {
    int i = base + tx;
    int v = (i < nbk) ? bcnt[i] : 0;
    s[tx] = v;
    __syncthreads();
    for (int d = 1; d < TPB; d <<= 1) {
      int t = (tx >= d) ? s[tx - d] : 0;
      __syncthreads();
      s[tx] += t;
      __syncthreads();
    }
    int c = carry;
    if (i < nbk) bbase[i] = c + s[tx] - v;
    __syncthreads();
    if (tx == TPB - 1) carry = c + s[tx];
    __syncthreads();
  }
}

__global__ __launch_bounds__(256) void per_bucket_build(
    const unsigned int* __restrict__ be, const int* __restrict__ bcnt,
    const int* __restrict__ bbase, int* __restrict__ off, int* __restrict__ col,
    int n, int e) {
  int b = blockIdx.x, tx = threadIdx.x;
  int cnt = bcnt[b];
  if (cnt > BCAP) cnt = BCAP;
  int base = bbase[b];
  int node0 = b << 7;
  __shared__ int scnt[128];
  __shared__ int sscan[128];
  if (tx < 128) scnt[tx] = 0;
  __syncthreads();
  const unsigned int* eb = be + (size_t)b * BCAP;
  for (int i = tx; i < cnt; i += 256) atomicAdd(&scnt[eb[i] >> 17], 1);
  __syncthreads();
  if (tx < 128) sscan[tx] = scnt[tx];
  __syncthreads();
  for (int d = 1; d < 128; d <<= 1) {
    int t = 0;
    if (tx < 128 && tx >= d) t = sscan[tx - d];
    __syncthreads();
    if (tx < 128) sscan[tx] += t;
    __syncthreads();
  }
  if (tx < 128) {
    int excl = sscan[tx] - scnt[tx];
    if (node0 + tx < n) off[node0 + tx] = base + excl;
    scnt[tx] = excl;  // becomes fill cursor
  }
  if (b == 0 && tx == 0) off[n] = e;
  __syncthreads();
  for (int i = tx; i < cnt; i += 256) {
    unsigned int u = eb[i];
    int p = atomicAdd(&scnt[u >> 17], 1);
    col[base + p] = (int)(u & 0x1ffff);
  }
}

// ---------------- converts ----------------

__global__ void f32_to_bf16_v4(const float* __restrict__ in, unsigned short* __restrict__ out,
                               int n4) {
  int i = blockIdx.x * TPB + threadIdx.x;
  if (i >= n4) return;
  float4 v = ((const float4*)in)[i];
  ushort4 o;
  o.x = f2bf(v.x); o.y = f2bf(v.y); o.z = f2bf(v.z); o.w = f2bf(v.w);
  ((ushort4*)out)[i] = o;
}

__global__ void make_dropmask(const float* __restrict__ u, unsigned char* __restrict__ m,
                              int n4) {
  int i = blockIdx.x * TPB + threadIdx.x;
  if (i >= n4) return;
  float4 v = ((const float4*)u)[i];
  uchar4 o;
  o.x = (v.x >= 0.2f) ? 1 : 0;
  o.y = (v.y >= 0.2f) ? 1 : 0;
  o.z = (v.z >= 0.2f) ? 1 : 0;
  o.w = (v.w >= 0.2f) ? 1 : 0;
  ((uchar4*)m)[i] = o;
}

// layer-1 weights: Wt1[128 out][256 K] = concat(W1l;W1r) transposed
template <int NF>
__global__ void build_wt(const float* __restrict__ Wl, const float* __restrict__ Wr,
                         unsigned short* __restrict__ Wt) {
  int idx = blockIdx.x * TPB + threadIdx.x;
  if (idx >= NF * 256) return;
  int nn = idx >> 8;
  int k = idx & 255;
  float v = (k < 128) ? Wl[k * NF + nn] : Wr[(k - 128) * NF + nn];
  Wt[idx] = f2bf(v);
}

// layer-2' weights: Wt2[128 out][128 K]; rows 0-63 = W2l^T (-> P), 64-127 = W2r^T (-> Q)
__global__ void build_wt2p(const float* __restrict__ W2l, const float* __restrict__ W2r,
                           unsigned short* __restrict__ Wt) {
  int idx = blockIdx.x * TPB + threadIdx.x;
  if (idx >= 128 * 128) return;
  int nn = idx >> 7;
  int k = idx & 127;
  float v = (nn < 64) ? W2l[k * 64 + nn] : W2r[k * 64 + (nn - 64)];
  Wt[idx] = f2bf(v);
}

// ---------------- layer-1 mean aggregation: 16 lanes per node (R3-proven) ----------
// One wave = 4 nodes. Per chunk of 16 edges, lane li preloads col[s0+base+li]
// (clamped to s1-1), then 16 unrolled iterations broadcast c via shfl(width=16)
// and gather uint4 at X + c*128 + li*8. 16 in-flight gathers/lane-group fits
// 48 VGPRs; the R5 2-node interleave needed ~128 VGPRs of load data and
// SPILLED (WRITE_SIZE 25->158MB, dur 66->136us). Do not widen without
// checking kernel-resource-usage.

__global__ void aggregate_bf(const unsigned short* __restrict__ X,
                             const int* __restrict__ off, const int* __restrict__ col,
                             unsigned short* __restrict__ out, int n) {
  int wv = (blockIdx.x * TPB + threadIdx.x) >> 6;
  int lane = threadIdx.x & 63;
  int li = lane & 15;
  int node = wv * 4 + (lane >> 4);
  if (node >= n) return;
  int s0 = off[node], s1 = off[node + 1];
  int cnt = s1 - s0;

  float a0 = 0.f, a1 = 0.f, a2 = 0.f, a3 = 0.f,
        a4 = 0.f, a5 = 0.f, a6 = 0.f, a7 = 0.f;

  for (int base = 0; base < cnt; base += 16) {
    int idx = s0 + base + li;
    int ci = col[min(idx, s1 - 1)];
    int lim = cnt - base;  // >0, group-uniform
#pragma unroll
    for (int j = 0; j < 16; ++j) {
      int c = __shfl(ci, j, 16);
      const uint4* p = (const uint4*)(X + (size_t)c * 128 + li * 8);
      uint4 v = *p;
      float s = (j < lim) ? 1.f : 0.f;
      a0 = fmaf(s, __uint_as_float(v.x << 16), a0);
      a1 = fmaf(s, __uint_as_float(v.x & 0xffff0000u), a1);
      a2 = fmaf(s, __uint_as_float(v.y << 16), a2);
      a3 = fmaf(s, __uint_as_float(v.y & 0xffff0000u), a3);
      a4 = fmaf(s, __uint_as_float(v.z << 16), a4);
      a5 = fmaf(s, __uint_as_float(v.z & 0xffff0000u), a5);
      a6 = fmaf(s, __uint_as_float(v.w << 16), a6);
      a7 = fmaf(s, __uint_as_float(v.w & 0xffff0000u), a7);
    }
  }

  float inv = (cnt > 0) ? 1.0f / (float)cnt : 0.f;
  uint4 o;
  o.x = ((unsigned int)f2bf(a1 * inv) << 16) | f2bf(a0 * inv);
  o.y = ((unsigned int)f2bf(a3 * inv) << 16) | f2bf(a2 * inv);
  o.z = ((unsigned int)f2bf(a5 * inv) << 16) | f2bf(a4 * inv);
  o.w = ((unsigned int)f2bf(a7 * inv) << 16) | f2bf(a6 * inv);
  *(uint4*)(out + (size_t)node * 128 + li * 8) = o;
}

// ---------------- layer-2 fused aggregate+add+ELU over P (64-dim, 128B rows) ----------
// mean commutes with W2l: out = elu(mean_j(P_j) + Q), P = h@W2l (bf16), Q = h@W2r+b2
// (f32). Rows are 128B -> 8 lanes x uint4; wave = 8 nodes; chunk of 8 edges.
// Gather volume halves vs aggregating h (256B rows). Per-lane in-flight loads: 8
// (uint4) = 32 VGPRs of data -> no spill (R5 measured, stayed off top-5).

__global__ void aggregate_add(const unsigned short* __restrict__ P,
                              const int* __restrict__ off, const int* __restrict__ col,
                              const float* __restrict__ Q, float* __restrict__ out, int n) {
  int wv = (blockIdx.x * TPB + threadIdx.x) >> 6;
  int lane = threadIdx.x & 63;
  int li = lane & 7;
  int node = wv * 8 + (lane >> 3);
  bool alive = node < n;
  int s0 = 0, s1 = 0;
  if (alive) { s0 = off[node]; s1 = off[node + 1]; }
  int cnt = s1 - s0;

  float a0 = 0.f, a1 = 0.f, a2 = 0.f, a3 = 0.f,
        a4 = 0.f, a5 = 0.f, a6 = 0.f, a7 = 0.f;

  for (int base = 0; base < cnt; base += 8) {
    int ci = col[max(0, min(s0 + base + li, s1 - 1))];
    int lim = cnt - base;
#pragma unroll
    for (int j = 0; j < 8; ++j) {
      int c = __shfl(ci, j, 8);
      uint4 v = *(const uint4*)(P + (size_t)c * 64 + li * 8);
      float s = (j < lim) ? 1.f : 0.f;
      a0 = fmaf(s, __uint_as_float(v.x << 16), a0);
      a1 = fmaf(s, __uint_as_float(v.x & 0xffff0000u), a1);
      a2 = fmaf(s, __uint_as_float(v.y << 16), a2);
      a3 = fmaf(s, __uint_as_float(v.y & 0xffff0000u), a3);
      a4 = fmaf(s, __uint_as_float(v.z << 16), a4);
      a5 = fmaf(s, __uint_as_float(v.z & 0xffff0000u), a5);
      a6 = fmaf(s, __uint_as_float(v.w << 16), a6);
      a7 = fmaf(s, __uint_as_float(v.w & 0xffff0000u), a7);
    }
  }

  if (alive) {
    float inv = (cnt > 0) ? 1.0f / (float)cnt : 0.f;
    const float4* qp = (const float4*)(Q + (size_t)node * 64 + li * 8);
    float4 q0 = qp[0], q1 = qp[1];
    float4 o0, o1;
    o0.x = a0 * inv + q0.x; o0.y = a1 * inv + q0.y;
    o0.z = a2 * inv + q0.z; o0.w = a3 * inv + q0.w;
    o1.x = a4 * inv + q1.x; o1.y = a5 * inv + q1.y;
    o1.z = a6 * inv + q1.z; o1.w = a7 * inv + q1.w;
    o0.x = (o0.x > 0.f) ? o0.x : expm1f(o0.x);
    o0.y = (o0.y > 0.f) ? o0.y : expm1f(o0.y);
    o0.z = (o0.z > 0.f) ? o0.z : expm1f(o0.z);
    o0.w = (o0.w > 0.f) ? o0.w : expm1f(o0.w);
    o1.x = (o1.x > 0.f) ? o1.x : expm1f(o1.x);
    o1.y = (o1.y > 0.f) ? o1.y : expm1f(o1.y);
    o1.z = (o1.z > 0.f) ? o1.z : expm1f(o1.z);
    o1.w = (o1.w > 0.f) ? o1.w : expm1f(o1.w);
    float4* op = (float4*)(out + (size_t)node * 64 + li * 8);
    op[0] = o0; op[1] = o1;
  }
}

// ---------------- MFMA GEMM: 128x64 blocks, counted-vmcnt double-buffer ----------------
// Block = 128 rows x 64 output cols (blockIdx.y picks the 64-col slab of Wt).
// NCH = K/64 chunks. MODE 0: ELU+dropout -> bf16[row][128] (layer 1).
// MODE 1: split epilogue: gcol<64 -> P bf16[row][64] (no bias), gcol>=64 ->
// Q=v+bias f32[row][64] (layer 2'). 48KB LDS -> 3 blocks/CU; pipeline: issue
// c0,c1; per chunk waitvm(6), barrier, compute, lgkmcnt(0)+barrier, issue c+2.

template <int NCH, int MODE>
__global__ __launch_bounds__(256) void gemm_mfma(
    const unsigned short* __restrict__ A1, const unsigned short* __restrict__ A2,
    const unsigned short* __restrict__ Wt, const float* __restrict__ bias,
    const unsigned char* __restrict__ dmask, unsigned short* __restrict__ outb,
    float* __restrict__ outf, int n) {
  constexpr int IPC = 6;      // DMA issues per thread per chunk: 4 A + 2 B
  constexpr int KTOT = NCH * 64;
  __shared__ __align__(16) unsigned short sA[2][128 * 64];
  __shared__ __align__(16) unsigned short sB[2][64 * 64];

  int tid = threadIdx.x;
  int row0 = blockIdx.x * 128;
  int ncol0 = blockIdx.y * 64;
  int lane = tid & 63;
  int wid = tid >> 6;
  int wm = wid >> 1, wn = wid & 1;
  int lq = lane & 15, q = lane >> 4;

  int sr = tid >> 3, sc8 = tid & 7;          // staging slot: row sr (+t*32), chunk sc8
  int cg = sc8 ^ (sr & 7);                   // global chunk this lane fetches (XOR swizzle)

  // clamped A rows for the 4 staging sub-tiles (chunk-invariant)
  int arow[4];
#pragma unroll
  for (int t = 0; t < 4; ++t) arow[t] = min(row0 + sr + t * 32, n - 1);

  f32x4 acc[4][2];
#pragma unroll
  for (int i = 0; i < 4; ++i)
#pragma unroll
    for (int j = 0; j < 2; ++j) acc[i][j] = (f32x4)(0.f);

  // issue all DMA for chunk c into buffer b (IPC insts per thread)
  auto issue = [&](int c, int b) {
    const unsigned short* Asrc = (c < 2) ? A1 : A2;
    int koff = (c & 1) * 64;
#pragma unroll
    for (int t = 0; t < 4; ++t) {
      gload16(Asrc + (size_t)arow[t] * 128 + koff + cg * 8,
              (char*)sA[b] + t * 4096 + wid * 1024);
    }
#pragma unroll
    for (int t = 0; t < 2; ++t) {
      gload16(Wt + (size_t)(ncol0 + sr + t * 32) * KTOT + c * 64 + cg * 8,
              (char*)sB[b] + t * 4096 + wid * 1024);
    }
  };

  issue(0, 0);
  issue(1, 1);

#pragma unroll
  for (int c = 0; c < NCH; ++c) {
    // wait: current chunk's IPC loads landed; next chunk's may stay in flight
    if (c < NCH - 1) waitvm<IPC>(); else waitvm<0>();
    __builtin_amdgcn_s_barrier();
    __builtin_amdgcn_sched_barrier(0);

    const int buf = c & 1;
#pragma unroll
    for (int ks = 0; ks < 2; ++ks) {
      bf16x8 a[4], b[2];
#pragma unroll
      for (int i = 0; i < 4; ++i) {
        int rr = wm * 64 + i * 16 + lq;
        a[i] = *(const bf16x8*)(&sA[buf][rr * 64 + (((ks * 4 + q) ^ (rr & 7)) * 8)]);
      }
#pragma unroll
      for (int j = 0; j < 2; ++j) {
        int rb = wn * 32 + j * 16 + lq;
        b[j] = *(const bf16x8*)(&sB[buf][rb * 64 + (((ks * 4 + q) ^ (rb & 7)) * 8)]);
      }
#pragma unroll
      for (int i = 0; i < 4; ++i)
#pragma unroll
        for (int j = 0; j < 2; ++j)
          acc[i][j] = __builtin_amdgcn_mfma_f32_16x16x32_bf16(a[i], b[j], acc[i][j], 0, 0, 0);
    }

    if (c < NCH - 2) {
      // all fragment ds_reads serviced before anyone overwrites this buffer
      asm volatile("s_waitcnt lgkmcnt(0)" ::: "memory");
      __builtin_amdgcn_sched_barrier(0);
      __builtin_amdgcn_s_barrier();
      issue(c + 2, buf);
    }
  }

#pragma unroll
  for (int j = 0; j < 2; ++j) {
    int gcol = ncol0 + wn * 32 + j * 16 + lq;
    float bv;
    if (MODE == 0) bv = bias[gcol];
    else bv = (gcol >= 64) ? bias[gcol - 64] : 0.f;
#pragma unroll
    for (int i = 0; i < 4; ++i) {
      int rbase = row0 + wm * 64 + i * 16 + q * 4;
#pragma unroll
      for (int r = 0; r < 4; ++r) {
        int row = rbase + r;
        if (row >= n) continue;
        float v = acc[i][j][r] + bv;
        if (MODE == 0) {
          v = (v > 0.f) ? v : expm1f(v);
          unsigned char k = dmask[(size_t)row * 128 + gcol];
          v = k ? v * 1.25f : 0.f;
          outb[(size_t)row * 128 + gcol] = f2bf(v);
        } else {
          if (gcol < 64) outb[(size_t)row * 64 + gcol] = f2bf(v);
          else outf[(size_t)row * 64 + (gcol - 64)] = v;
        }
      }
    }
  }
}

// ---------------- launch ----------------

extern "C" void kernel_launch(void* const* d_in, const int* in_sizes, int n_in,
                              void* d_out, int out_size, void* d_ws, size_t ws_size,
                              hipStream_t stream) {
  const float* x = (const float*)d_in[0];
  const int* ei = (const int*)d_in[1];
  const float* dropu = (const float*)d_in[2];
  const float* W1l = (const float*)d_in[3];
  const float* W1r = (const float*)d_in[4];
  const float* b1 = (const float*)d_in[5];
  const float* W2l = (const float*)d_in[6];
  const float* W2r = (const float*)d_in[7];
  const float* b2 = (const float*)d_in[8];

  int n = in_sizes[0] / 128;
  int e = in_sizes[1] / 2;
  const int* src = ei;
  const int* dst = ei + e;
  float* out = (float*)d_out;

  char* w = (char*)d_ws;
  auto alloc = [&](size_t bytes) -> char* {
    char* p = w;
    w += (bytes + 255) & ~(size_t)255;
    return p;
  };
  int nbk = (n + 127) / 128;  // buckets of 128 nodes (782)
  int* off = (int*)alloc((size_t)(n + 1) * sizeof(int));
  int* col = (int*)alloc((size_t)e * sizeof(int));
  int* bcnt = (int*)alloc((size_t)nbk * sizeof(int));
  int* bbase = (int*)alloc((size_t)nbk * sizeof(int));
  unsigned short* xb = (unsigned short*)alloc((size_t)n * 128 * 2);
  unsigned short* hb = (unsigned short*)alloc((size_t)n * 128 * 2);
  unsigned short* aggb = (unsigned short*)alloc((size_t)n * 128 * 2);
  unsigned char* dmask = (unsigned char*)alloc((size_t)n * 128);
  unsigned short* Wt1 = (unsigned short*)alloc(128 * 256 * 2);
  unsigned short* Wt2 = (unsigned short*)alloc(128 * 128 * 2);
  // overlays (stream-ordered lifetimes):
  //   be (8.0MB)  -> aggb region: dead before agg1 writes aggb
  //   pb (12.8MB) -> xb region:   xb dead after gemm1 (A2 input)
  //   qf (25.6MB) -> aggb region: aggb dead after gemm1 (A1 input)
  unsigned int* be = (unsigned int*)aggb;
  unsigned short* pb = xb;
  float* qf = (float*)aggb;

  hipMemsetAsync(bcnt, 0, (size_t)nbk * sizeof(int), stream);

  int gMS = (e + EPB - 1) / EPB;
  multisplit_scatter<<<gMS, TPB, 0, stream>>>(src, dst, be, bcnt, e, nbk);
  bucket_scan<<<1, TPB, 0, stream>>>(bcnt, bbase, nbk);
  per_bucket_build<<<nbk, TPB, 0, stream>>>(be, bcnt, bbase, off, col, n, e);

  int n4 = n * 128 / 4;
  f32_to_bf16_v4<<<(n4 + TPB - 1) / TPB, TPB, 0, stream>>>(x, xb, n4);
  make_dropmask<<<(n4 + TPB - 1) / TPB, TPB, 0, stream>>>(dropu, dmask, n4);
  build_wt<128><<<(128 * 256 + TPB - 1) / TPB, TPB, 0, stream>>>(W1l, W1r, Wt1);
  build_wt2p<<<(128 * 128 + TPB - 1) / TPB, TPB, 0, stream>>>(W2l, W2r, Wt2);

  int gAgg1 = ((n + 3) / 4 * 64 + TPB - 1) / TPB;  // 16 lanes/node, 4 nodes/wave
  int gAgg2 = (n + 31) / 32;                       // 8 lanes/node, 8 nodes/wave
  int gR = (n + 127) / 128;

  // layer 1: agg(x) -> gemm (K=256: [agg|x]) -> elu+drop -> hb
  aggregate_bf<<<gAgg1, TPB, 0, stream>>>(xb, off, col, aggb, n);
  gemm_mfma<4, 0><<<dim3(gR, 2), TPB, 0, stream>>>(aggb, xb, Wt1, b1, dmask, hb, nullptr, n);

  // layer 2 (mean commuted with W2l): P=h@W2l (bf16), Q=h@W2r+b2 (f32),
  // out = elu(mean_j P_j + Q)
  gemm_mfma<2, 1><<<dim3(gR, 2), TPB, 0, stream>>>(hb, nullptr, Wt2, b2, nullptr, pb, qf, n);
  aggregate_add<<<gAgg2, TPB, 0, stream>>>(pb, off, col, qf, out, n);
}